// Round 5
// baseline (879.387 us; speedup 1.0000x reference)
//
#include <hip/hip_runtime.h>
#include <hip/hip_bf16.h>
#include <string.h>

typedef __attribute__((ext_vector_type(8))) short short8;
typedef __attribute__((ext_vector_type(4))) float f32x4;
typedef unsigned long long ull;

#define NN 50000
#define NE 600000
#define GXc 782    // ceil(50000/64)
#define ABc 12500  // ceil(50000/4)

__device__ __forceinline__ unsigned short f32_bf16(float f) {
  unsigned u = __float_as_uint(f);
  unsigned r = u + 0x7FFFu + ((u >> 16) & 1u);
  return (unsigned short)(r >> 16);
}
__device__ __forceinline__ float bf_lo(unsigned v) { return __uint_as_float(v << 16); }
__device__ __forceinline__ float bf_hi(unsigned v) { return __uint_as_float(v & 0xFFFF0000u); }

// ---------------- fused transpose of all 7 weights ----------------
struct TransDesc { const float* src; unsigned short* dst; int K, Nn, Kpad, base; };
struct TransArgs { TransDesc d[7]; int total; };

__global__ void transpose_all_kernel(TransArgs a) {
  int idx = blockIdx.x * 256 + threadIdx.x;
  if (idx >= a.total) return;
  int s = 0;
#pragma unroll
  for (int q = 1; q < 7; ++q)
    if (idx >= a.d[q].base) s = q;
  TransDesc t = a.d[s];
  int off = idx - t.base;
  int n = off / t.Kpad, k = off % t.Kpad;
  float v = (k < t.K) ? t.src[(size_t)k * t.Nn + n] : 0.f;
  t.dst[off] = f32_bf16(v);
}

// ---------------- GEMM body (bf16 MFMA, BM=64, register prefetch, dynamic LDS) ----
template <int BN, bool ABF16, bool PRED>
__device__ __forceinline__ void gemm_body(char* ldsraw, const void* __restrict__ Av,
                                          const unsigned short* __restrict__ BT,
                                          unsigned short* __restrict__ C, int M, int K, int Kpad,
                                          int ldc, const float* fbias, const float* Wp,
                                          const float* bp, float* pout, int bx) {
  constexpr int BM = 64, BK = 32, LW = BK + 8;
  unsigned short* As = (unsigned short*)ldsraw;
  unsigned short* Bs = As + BM * LW;
  const int tid = threadIdx.x;
  const int m0 = bx * BM;
  const int wid = tid >> 6, lane = tid & 63;
  constexpr int WC = (BN == 128) ? 2 : 1;
  constexpr int WTM = (BN == 128) ? 32 : 16;
  constexpr int FM = WTM / 16;
  constexpr int FN = 4;
  const int wr = wid / WC, wc = wid % WC;
  const int rowbase = wr * WTM, colbase = wc * 64;
  const int lrow = lane & 15, lk = lane >> 4;

  const float* Af = (const float*)Av;
  const unsigned short* Ah = (const unsigned short*)Av;

  f32x4 acc[FM][FN] = {};
  float4 arf[2];
  short8 arh;
  short8 brr[BN / 64];

  const int nt = Kpad / BK;

  auto loadA = [&](int k0) {
    if (ABF16) {
      int row = tid >> 2, c8 = tid & 3;
      int gr = m0 + row;
      if (gr >= M) gr = M - 1;
      arh = *(const short8*)(Ah + (size_t)gr * K + k0 + c8 * 8);
    } else {
#pragma unroll
      for (int p = 0; p < 2; ++p) {
        int f = tid + p * 256;
        int row = f >> 3, c4 = f & 7;
        int gr = m0 + row;
        if (gr >= M) gr = M - 1;
        int gk = k0 + c4 * 4;
        float4 v = make_float4(0.f, 0.f, 0.f, 0.f);
        const float* base = Af + (size_t)gr * K + gk;
        if (gk + 4 <= K) {
          v = *(const float4*)base;
        } else {
          if (gk + 0 < K) v.x = base[0];
          if (gk + 1 < K) v.y = base[1];
          if (gk + 2 < K) v.z = base[2];
          if (gk + 3 < K) v.w = base[3];
        }
        arf[p] = v;
      }
    }
  };
  auto loadB = [&](int k0) {
#pragma unroll
    for (int p = 0; p < BN / 64; ++p) {
      int f = tid + p * 256;
      int n = f >> 2, c8 = f & 3;
      brr[p] = *(const short8*)(BT + (size_t)n * Kpad + k0 + c8 * 8);
    }
  };
  auto storeAB = [&]() {
    if (ABF16) {
      int row = tid >> 2, c8 = tid & 3;
      *reinterpret_cast<short8*>(&As[row * LW + c8 * 8]) = arh;
    } else {
#pragma unroll
      for (int p = 0; p < 2; ++p) {
        int f = tid + p * 256;
        int row = f >> 3, c4 = f & 7;
        unsigned a0 = (unsigned)f32_bf16(arf[p].x) | ((unsigned)f32_bf16(arf[p].y) << 16);
        unsigned a1 = (unsigned)f32_bf16(arf[p].z) | ((unsigned)f32_bf16(arf[p].w) << 16);
        *reinterpret_cast<uint2*>(&As[row * LW + c4 * 4]) = make_uint2(a0, a1);
      }
    }
#pragma unroll
    for (int p = 0; p < BN / 64; ++p) {
      int f = tid + p * 256;
      int n = f >> 2, c8 = f & 3;
      *reinterpret_cast<short8*>(&Bs[n * LW + c8 * 8]) = brr[p];
    }
  };

  loadA(0);
  loadB(0);
  for (int kt = 0; kt < nt; ++kt) {
    if (kt) __syncthreads();
    storeAB();
    __syncthreads();
    if (kt + 1 < nt) {
      loadA((kt + 1) * BK);
      loadB((kt + 1) * BK);
    }
    short8 af[FM], bf[FN];
#pragma unroll
    for (int i = 0; i < FM; ++i)
      af[i] = *reinterpret_cast<const short8*>(&As[(rowbase + i * 16 + lrow) * LW + lk * 8]);
#pragma unroll
    for (int j = 0; j < FN; ++j)
      bf[j] = *reinterpret_cast<const short8*>(&Bs[(colbase + j * 16 + lrow) * LW + lk * 8]);
#pragma unroll
    for (int i = 0; i < FM; ++i)
#pragma unroll
      for (int j = 0; j < FN; ++j)
        acc[i][j] = __builtin_amdgcn_mfma_f32_16x16x32_bf16(af[i], bf[j], acc[i][j], 0, 0, 0);
  }

  if (PRED) {
    float p0[4] = {0.f, 0.f, 0.f, 0.f}, p1[4] = {0.f, 0.f, 0.f, 0.f};
#pragma unroll
    for (int j = 0; j < FN; ++j) {
      int col = j * 16 + lrow;
      float w0 = Wp[col * 2], w1 = Wp[col * 2 + 1];
      float fb = fbias[col];
#pragma unroll
      for (int q = 0; q < 4; ++q) {
        float v = fmaxf(acc[0][j][q] + fb, 0.f);
        p0[q] += v * w0;
        p1[q] += v * w1;
      }
    }
#pragma unroll
    for (int o = 1; o < 16; o <<= 1) {
#pragma unroll
      for (int q = 0; q < 4; ++q) {
        p0[q] += __shfl_xor(p0[q], o);
        p1[q] += __shfl_xor(p1[q], o);
      }
    }
    if (lrow == 0) {
#pragma unroll
      for (int q = 0; q < 4; ++q) {
        int row = m0 + rowbase + lk * 4 + q;
        if (row < M) {
          pout[(size_t)row * 2 + 0] = p0[q] + bp[0];
          pout[(size_t)row * 2 + 1] = p1[q] + bp[1];
        }
      }
    }
  } else {
#pragma unroll
    for (int i = 0; i < FM; ++i) {
#pragma unroll
      for (int j = 0; j < FN; ++j) {
#pragma unroll
        for (int q = 0; q < 4; ++q) {
          int row = m0 + rowbase + i * 16 + lk * 4 + q;
          int col = colbase + j * 16 + lrow;
          if (row < M) C[(size_t)row * ldc + col] = f32_bf16(acc[i][j][q]);
        }
      }
    }
  }
}

// ---------------- mega kernel roles ----------------
struct EdgeArgs { const int* ei[3]; const float* ew[3]; };

struct MegaArgs {
  int nEdge, eMode, eBr, eBlocks;
  int nG1, nG2, nA128, nA64;
  // G1 (up to 3 slots, GXc blocks each)
  const float* g1A[3]; const unsigned short* g1B[3]; unsigned short* g1C[3];
  int g1K[3], g1Kp[3];
  // G2 / fuse+pred
  const unsigned short* g2A; const unsigned short* g2B; unsigned short* g2C;
  int fPred; const float* fBias; const float* fWp; const float* fBp; float* fOut;
  // agg128
  const unsigned short* aX; const float* aDinv; const int* aOff; const ull* aPc;
  const int2* aCsr; const float* aBias; unsigned short* aOut;
  // agg64
  const unsigned short* bX; const float* bDinv; const int* bOff; const ull* bPc;
  const int2* bCsr; const float* bBias; unsigned short* bOut; int bLdo, bCoff;
  // edge shared state
  EdgeArgs ea;
  ull* pcp;                  // [8][3*NN] privatized packed (count<<32 | fix24 wsum)
  unsigned short* rank;      // [3*NE]: (copy<<13 | local rank)
  const int* off3;           // [3*NN]
  const unsigned short* pref8;  // [8][3*NN] per-copy exclusive prefix
  int2* csrW;                // [3*NE] {src, norm bits}
  const float* dinv3;        // [3*NN]
};

__device__ void edge_body(const MegaArgs& a, int bx) {
  if (a.eMode == 0) {
    int copy = (int)(blockIdx.x & 7);
    ull* pcc = a.pcp + (size_t)copy * (3 * NN);
    const int stride = a.eBlocks * 256;
    for (int idx = bx * 256 + (int)threadIdx.x; idx < 3 * NE; idx += stride) {
      int b = (idx >= 2 * NE) ? 2 : ((idx >= NE) ? 1 : 0);
      int e = idx - b * NE;
      const int* ei = a.ea.ei[b];
      int d = ei[NE + e];
      float w = a.ea.ew[b][e];
      ull pkt = (1ull << 32) | (ull)(unsigned)(w * 16777216.0f);
      ull old = atomicAdd(&pcc[b * NN + d], pkt);
      a.rank[idx] = (unsigned short)(((unsigned)copy << 13) | (unsigned)(old >> 32));
    }
  } else {
    int b = a.eBr;
    const int* ei = a.ea.ei[b];
    const float* ew = a.ea.ew[b];
    const float* dinv = a.dinv3 + (size_t)b * NN;
    const int stride = a.eBlocks * 256;
    for (int e = bx * 256 + (int)threadIdx.x; e < NE; e += stride) {
      unsigned rw = a.rank[(size_t)b * NE + e];
      int copy = rw >> 13, lr = rw & 8191;
      int d = ei[NE + e], s = ei[e];
      int t = a.off3[b * NN + d] + (int)a.pref8[(size_t)copy * (3 * NN) + b * NN + d] + lr;
      float cw = dinv[s] * ew[e] * dinv[d];
      a.csrW[(size_t)b * NE + t] = make_int2(s, __float_as_int(cw));
    }
  }
}

__device__ void agg128_body(const MegaArgs& a, int t) {
  int i = (t << 2) + ((int)threadIdx.x >> 6);
  if (i >= NN) return;
  int lane = threadIdx.x & 63;
  const unsigned short* x = a.aX;
  float di = a.aDinv[i];
  unsigned sv = *(const unsigned*)(x + (size_t)i * 128 + lane * 2);
  float w0 = di * di;
  float acc0 = bf_lo(sv) * w0, acc1 = bf_hi(sv) * w0;
  int cnt = (int)(a.aPc[i] >> 32);
  const int2* cp = a.aCsr + a.aOff[i];
  for (int t2 = 0; t2 < cnt; ++t2) {
    int2 sl = cp[t2];
    float wt = __int_as_float(sl.y);
    unsigned v = *(const unsigned*)(x + (size_t)sl.x * 128 + lane * 2);
    acc0 += bf_lo(v) * wt;
    acc1 += bf_hi(v) * wt;
  }
  acc0 = fmaxf(acc0 + a.aBias[lane * 2], 0.f);
  acc1 = fmaxf(acc1 + a.aBias[lane * 2 + 1], 0.f);
  unsigned o = (unsigned)f32_bf16(acc0) | ((unsigned)f32_bf16(acc1) << 16);
  *(unsigned*)(a.aOut + (size_t)i * 128 + lane * 2) = o;
}

__device__ void agg64_body(const MegaArgs& a, int t) {
  int i = (t << 2) + ((int)threadIdx.x >> 6);
  if (i >= NN) return;
  int lane = threadIdx.x & 63;
  int half = lane >> 5, l2 = (lane & 31) * 2;
  const unsigned short* x = a.bX;
  float di = a.bDinv[i];
  float acc0 = 0.f, acc1 = 0.f;
  if (half == 0) {
    unsigned sv = *(const unsigned*)(x + (size_t)i * 64 + l2);
    float w0 = di * di;
    acc0 = bf_lo(sv) * w0;
    acc1 = bf_hi(sv) * w0;
  }
  int cnt = (int)(a.bPc[i] >> 32);
  const int2* cp = a.bCsr + a.bOff[i];
  for (int t2 = half; t2 < cnt; t2 += 2) {
    int2 sl = cp[t2];
    float wt = __int_as_float(sl.y);
    unsigned v = *(const unsigned*)(x + (size_t)sl.x * 64 + l2);
    acc0 += bf_lo(v) * wt;
    acc1 += bf_hi(v) * wt;
  }
  acc0 += __shfl_xor(acc0, 32);
  acc1 += __shfl_xor(acc1, 32);
  if (half == 0) {
    acc0 = fmaxf(acc0 + a.bBias[l2], 0.f);
    acc1 = fmaxf(acc1 + a.bBias[l2 + 1], 0.f);
    unsigned o = (unsigned)f32_bf16(acc0) | ((unsigned)f32_bf16(acc1) << 16);
    *(unsigned*)(a.bOut + (size_t)i * a.bLdo + a.bCoff + l2) = o;
  }
}

__global__ __launch_bounds__(256) void mega_kernel(MegaArgs a) {
  extern __shared__ char lds[];
  int bx = blockIdx.x;
  if (bx < a.nEdge) {
    edge_body(a, bx);
    return;
  }
  bx -= a.nEdge;
  if (bx < a.nG1) {
    int slot = bx / GXc, b2 = bx - slot * GXc;
    gemm_body<128, false, false>(lds, a.g1A[slot], a.g1B[slot], a.g1C[slot], NN, a.g1K[slot],
                                 a.g1Kp[slot], 128, nullptr, nullptr, nullptr, nullptr, b2);
    return;
  }
  bx -= a.nG1;
  if (bx < a.nG2) {
    if (a.fPred)
      gemm_body<64, true, true>(lds, a.g2A, a.g2B, nullptr, NN, 192, 192, 0, a.fBias, a.fWp,
                                a.fBp, a.fOut, bx);
    else
      gemm_body<64, true, false>(lds, a.g2A, a.g2B, a.g2C, NN, 128, 128, 64, nullptr, nullptr,
                                 nullptr, nullptr, bx);
    return;
  }
  bx -= a.nG2;
  if (bx < a.nA128) {
    agg128_body(a, bx);
    return;
  }
  bx -= a.nA128;
  agg64_body(a, bx);
}

// ---------------- scans: fold 8-copy reduce + per-copy prefix into scan1 ----------------
__global__ void scan1_kernel(const ull* __restrict__ pcp, unsigned short* __restrict__ pref8,
                             ull* __restrict__ pcTot, int* __restrict__ partial3,
                             int* __restrict__ bsums3, int n, int bpb) {
  __shared__ int sd[256];
  int b = blockIdx.x / bpb, blk = blockIdx.x % bpb;
  int i = blk * 256 + threadIdx.x;
  int tc = 0;
  if (i < n) {
    unsigned ws = 0;
#pragma unroll
    for (int c = 0; c < 8; ++c) {
      size_t idx = (size_t)c * (3 * NN) + b * NN + i;
      ull v = pcp[idx];
      pref8[idx] = (unsigned short)tc;
      tc += (int)(v >> 32);
      ws += (unsigned)(v & 0xFFFFFFFFull);
    }
    pcTot[b * NN + i] = ((ull)(unsigned)tc << 32) | ws;
  }
  sd[threadIdx.x] = tc;
  __syncthreads();
  for (int o = 1; o < 256; o <<= 1) {
    int t = (threadIdx.x >= o) ? sd[threadIdx.x - o] : 0;
    __syncthreads();
    sd[threadIdx.x] += t;
    __syncthreads();
  }
  if (i < n) partial3[b * NN + i] = sd[threadIdx.x];
  if (threadIdx.x == 255) bsums3[b * 256 + blk] = sd[255];
}

__global__ void scan2_kernel(int* __restrict__ bsums3, int nb) {
  __shared__ int sd[256];
  int b = blockIdx.x;
  int v = (threadIdx.x < nb) ? bsums3[b * 256 + threadIdx.x] : 0;
  sd[threadIdx.x] = v;
  __syncthreads();
  for (int o = 1; o < 256; o <<= 1) {
    int t = (threadIdx.x >= o) ? sd[threadIdx.x - o] : 0;
    __syncthreads();
    sd[threadIdx.x] += t;
    __syncthreads();
  }
  if (threadIdx.x < nb) bsums3[b * 256 + threadIdx.x] = sd[threadIdx.x] - v;
}

__global__ void scan3_kernel(const ull* __restrict__ pcTot, const int* __restrict__ partial3,
                             const int* __restrict__ bsums3, int* __restrict__ off3,
                             float* __restrict__ dinv3, int n, int bpb) {
  int b = blockIdx.x / bpb, blk = blockIdx.x % bpb;
  int i = blk * 256 + threadIdx.x;
  if (i >= n) return;
  ull v = pcTot[b * NN + i];
  int c = (int)(v >> 32);
  off3[b * NN + i] = partial3[b * NN + i] - c + bsums3[b * 256 + blk];
  float deg = (float)(unsigned)(v & 0xFFFFFFFFull) * (1.0f / 16777216.0f) + 1.0f;
  dinv3[b * NN + i] = rsqrtf(deg);
}

extern "C" void kernel_launch(void* const* d_in, const int* in_sizes, int n_in, void* d_out,
                              int out_size, void* d_ws, size_t ws_size, hipStream_t stream) {
  const int Ds[3] = {1000, 1000, 500};
  const int H1 = 128, H2 = 64;

  char* p = (char*)d_ws;
  auto carve = [&](size_t bytes) {
    void* r = (void*)p;
    p += (bytes + 255) & ~(size_t)255;
    return r;
  };

  unsigned short* w1t[3];
  int kpad1[3];
  for (int b = 0; b < 3; ++b) {
    kpad1[b] = (Ds[b] + 31) & ~31;
    w1t[b] = (unsigned short*)carve((size_t)H1 * kpad1[b] * 2);
  }
  unsigned short* w2t[3];
  for (int b = 0; b < 3; ++b) w2t[b] = (unsigned short*)carve((size_t)H2 * 128 * 2);
  unsigned short* wft = (unsigned short*)carve((size_t)H2 * 192 * 2);

  ull* pcp = (ull*)carve((size_t)8 * 3 * NN * 8);            // 9.6 MB
  ull* pcTot = (ull*)carve((size_t)3 * NN * 8);              // 1.2 MB
  unsigned short* pref8 = (unsigned short*)carve((size_t)8 * 3 * NN * 2);  // 2.4 MB
  float* dinv3 = (float*)carve((size_t)3 * NN * 4);
  int* partial3 = (int*)carve((size_t)3 * NN * 4);
  int* bsums3 = (int*)carve((size_t)3 * 256 * 4);
  int* off3 = (int*)carve((size_t)3 * NN * 4);
  unsigned short* rank = (unsigned short*)carve((size_t)3 * NE * 2);  // 3.6 MB
  int2* csr = (int2*)carve((size_t)3 * NE * 8);                       // 14.4 MB
  unsigned short* x1a = (unsigned short*)carve((size_t)NN * 128 * 2);
  unsigned short* x1b = (unsigned short*)carve((size_t)NN * 128 * 2);
  unsigned short* x1c = (unsigned short*)carve((size_t)NN * 128 * 2);
  unsigned short* h1a = (unsigned short*)carve((size_t)NN * 128 * 2);
  unsigned short* h1b = (unsigned short*)carve((size_t)NN * 128 * 2);
  unsigned short* x2a = (unsigned short*)carve((size_t)NN * 64 * 2);
  unsigned short* x2b = (unsigned short*)carve((size_t)NN * 64 * 2);
  unsigned short* comb = (unsigned short*)carve((size_t)NN * 192 * 2);

  const int nb = (NN + 255) / 256;  // 196

  // ---- transposes ----
  TransArgs ta;
  int base = 0;
  const float* wsrc[7] = {(const float*)d_in[3],  (const float*)d_in[10], (const float*)d_in[17],
                          (const float*)d_in[5],  (const float*)d_in[12], (const float*)d_in[19],
                          (const float*)d_in[21]};
  unsigned short* wdst[7] = {w1t[0], w1t[1], w1t[2], w2t[0], w2t[1], w2t[2], wft};
  int wK[7] = {1000, 1000, 500, 128, 128, 128, 192};
  int wN[7] = {128, 128, 128, 64, 64, 64, 64};
  int wKp[7] = {1024, 1024, 512, 128, 128, 128, 192};
  for (int s = 0; s < 7; ++s) {
    ta.d[s] = {wsrc[s], wdst[s], wK[s], wN[s], wKp[s], base};
    base += wN[s] * wKp[s];
  }
  ta.total = base;
  transpose_all_kernel<<<(base + 255) / 256, 256, 0, stream>>>(ta);
  hipMemsetAsync(pcp, 0, (size_t)8 * 3 * NN * 8, stream);

  // ---- base args ----
  MegaArgs baseArgs;
  memset(&baseArgs, 0, sizeof(baseArgs));
  for (int b = 0; b < 3; ++b) {
    baseArgs.ea.ei[b] = (const int*)d_in[b * 7 + 1];
    baseArgs.ea.ew[b] = (const float*)d_in[b * 7 + 2];
  }
  baseArgs.pcp = pcp;
  baseArgs.rank = rank;
  baseArgs.off3 = off3;
  baseArgs.pref8 = pref8;
  baseArgs.csrW = csr;
  baseArgs.dinv3 = dinv3;

  unsigned short* x1s[3] = {x1a, x1b, x1c};

  auto addG1 = [&](MegaArgs& m, int b, unsigned short* dst) {
    int s = m.nG1 / GXc;
    m.g1A[s] = (const float*)d_in[b * 7 + 0];
    m.g1B[s] = w1t[b];
    m.g1C[s] = dst;
    m.g1K[s] = Ds[b];
    m.g1Kp[s] = kpad1[b];
    m.nG1 += GXc;
  };
  auto setA128 = [&](MegaArgs& m, int b, const unsigned short* xin, unsigned short* hout) {
    m.nA128 = ABc;
    m.aX = xin;
    m.aDinv = dinv3 + (size_t)b * NN;
    m.aOff = off3 + b * NN;
    m.aPc = pcTot + (size_t)b * NN;
    m.aCsr = csr + (size_t)b * NE;
    m.aBias = (const float*)d_in[b * 7 + 4];
    m.aOut = hout;
  };
  auto setG2 = [&](MegaArgs& m, int b, const unsigned short* hin, unsigned short* xout) {
    m.nG2 = GXc;
    m.g2A = hin;
    m.g2B = w2t[b];
    m.g2C = xout;
    m.fPred = 0;
  };
  auto setFuse = [&](MegaArgs& m) {
    m.nG2 = GXc;
    m.g2A = comb;
    m.g2B = wft;
    m.g2C = nullptr;
    m.fPred = 1;
    m.fBias = (const float*)d_in[22];
    m.fWp = (const float*)d_in[23];
    m.fBp = (const float*)d_in[24];
    m.fOut = (float*)d_out;
  };
  auto setA64 = [&](MegaArgs& m, int b, const unsigned short* xin) {
    m.nA64 = ABc;
    m.bX = xin;
    m.bDinv = dinv3 + (size_t)b * NN;
    m.bOff = off3 + b * NN;
    m.bPc = pcTot + (size_t)b * NN;
    m.bCsr = csr + (size_t)b * NE;
    m.bBias = (const float*)d_in[b * 7 + 6];
    m.bOut = comb;
    m.bLdo = 192;
    m.bCoff = b * 64;
  };
  auto setCount = [&](MegaArgs& m) {
    m.nEdge = 2048;
    m.eBlocks = 2048;
    m.eMode = 0;
  };
  auto setScatter = [&](MegaArgs& m, int b) {
    m.nEdge = 1024;
    m.eBlocks = 1024;
    m.eMode = 1;
    m.eBr = b;
  };
  auto launch = [&](MegaArgs& m) {
    int g = m.nEdge + m.nG1 + m.nG2 + m.nA128 + m.nA64;
    size_t ldsb = (m.nG1 > 0) ? 15360 : ((m.nG2 > 0) ? 10240 : 0);
    mega_kernel<<<g, 256, ldsb, stream>>>(m);
  };

  MegaArgs m;
  // L2: count(all) + GEMM1 x3
  m = baseArgs;
  setCount(m);
  addG1(m, 0, x1s[0]);
  addG1(m, 1, x1s[1]);
  addG1(m, 2, x1s[2]);
  launch(m);
  // L3: scans (+dinv)
  scan1_kernel<<<3 * nb, 256, 0, stream>>>(pcp, pref8, pcTot, partial3, bsums3, NN, nb);
  scan2_kernel<<<3, 256, 0, stream>>>(bsums3, nb);
  scan3_kernel<<<3 * nb, 256, 0, stream>>>(pcTot, partial3, bsums3, off3, dinv3, NN, nb);
  // L4: scatter b0
  m = baseArgs;
  setScatter(m, 0);
  launch(m);
  // L5: scatter b1 + agg128 b0
  m = baseArgs;
  setScatter(m, 1);
  setA128(m, 0, x1s[0], h1a);
  launch(m);
  // L6: scatter b2 + gemm2 b0 + agg128 b1
  m = baseArgs;
  setScatter(m, 2);
  setG2(m, 0, h1a, x2a);
  setA128(m, 1, x1s[1], h1b);
  launch(m);
  // L7: gemm2 b1 + agg128 b2 + agg64 b0
  m = baseArgs;
  setG2(m, 1, h1b, x2b);
  setA128(m, 2, x1s[2], h1a);
  setA64(m, 0, x2a);
  launch(m);
  // L8: gemm2 b2 + agg64 b1
  m = baseArgs;
  setG2(m, 2, h1a, x2a);
  setA64(m, 1, x2b);
  launch(m);
  // L9: agg64 b2
  m = baseArgs;
  setA64(m, 2, x2a);
  launch(m);
  // L10: fuse + pred
  m = baseArgs;
  setFuse(m);
  launch(m);
}